// Round 5
// baseline (287.731 us; speedup 1.0000x reference)
//
#include <hip/hip_runtime.h>

#define B_  2
#define L_  4096
#define DM_ 1024
#define H_  16
#define D_  64
#define M_  (B_ * L_)   // 8192

typedef unsigned short u16;
typedef short bf16x8 __attribute__((ext_vector_type(8)));   // 8 bf16 (4 VGPRs)
typedef float f32x4  __attribute__((ext_vector_type(4)));   // MFMA accumulator

typedef const __attribute__((address_space(1))) void* as1_cvp;
typedef __attribute__((address_space(3))) void* as3_vp;

__device__ __forceinline__ float b2f(u16 u) {
    union { unsigned int i; float f; } x; x.i = ((unsigned int)u) << 16; return x.f;
}
__device__ __forceinline__ u16 f2b(float f) {   // RNE bf16
    unsigned int x = __float_as_uint(f);
    return (u16)((x + 0x7fffu + ((x >> 16) & 1u)) >> 16);
}

// ---------------------------------------------------------------------------
// prep: blocks [0, 24576): fp32->bf16 cast of q/k/v (8192 blocks each)
//       blocks [24576, 28672): W transpose+cast, 1024 blocks per weight
// ---------------------------------------------------------------------------
__global__ void prep_kernel(
    const float* __restrict__ query, const float* __restrict__ key, const float* __restrict__ value,
    u16* __restrict__ qb, u16* __restrict__ kb, u16* __restrict__ vb,
    const float* __restrict__ w0, const float* __restrict__ w1,
    const float* __restrict__ w2, const float* __restrict__ w3,
    u16* __restrict__ t0, u16* __restrict__ t1, u16* __restrict__ t2, u16* __restrict__ t3)
{
    __shared__ float tile[32][33];
    const int bx = blockIdx.x;
    const int t  = threadIdx.x;
    if (bx < 24576) {
        int z = bx >> 13;                 // /8192
        int i = (bx & 8191) * 256 + t;
        const float* in = z == 0 ? query : (z == 1 ? key : value);
        u16* out        = z == 0 ? qb    : (z == 1 ? kb  : vb);
        float4 v = ((const float4*)in)[i];
        ushort4 o;
        o.x = f2b(v.x); o.y = f2b(v.y); o.z = f2b(v.z); o.w = f2b(v.w);
        ((ushort4*)out)[i] = o;
    } else {
        int bz = bx - 24576;
        int z  = bz >> 10;
        int rem = bz & 1023;
        int gx = rem & 31, gy = rem >> 5;
        const float* W = z == 0 ? w0 : z == 1 ? w1 : z == 2 ? w2 : w3;
        u16* Wt        = z == 0 ? t0 : z == 1 ? t1 : z == 2 ? t2 : t3;
        int tx = t & 31, ty = t >> 5;     // 32 x 8
        int n  = gx * 32 + tx;
        int k0 = gy * 32;
#pragma unroll
        for (int i = 0; i < 4; ++i)
            tile[ty + i * 8][tx] = W[(size_t)(k0 + ty + i * 8) * DM_ + n];
        __syncthreads();
#pragma unroll
        for (int i = 0; i < 4; ++i) {
            int nn = gx * 32 + ty + i * 8;
            Wt[(size_t)nn * DM_ + k0 + tx] = f2b(tile[tx][ty + i * 8]);
        }
    }
}

// ---------------------------------------------------------------------------
// QKV projections batched via blockIdx.z (z=0:Q, 1:K -> per-head transposed
// +ELU+1 out; z=2:V -> natural bf16 out). m97 K-loop; 32 KB LDS total
// (Ct transpose reuses As+Bs, stride 128 no pad -> 5 blocks/CU by LDS).
// ---------------------------------------------------------------------------
__global__ __launch_bounds__(256, 4) void gemm_qkv_kernel(
    const u16* __restrict__ qb, const u16* __restrict__ kb, const u16* __restrict__ vb,
    const u16* __restrict__ Wqt, const u16* __restrict__ Wkt, const u16* __restrict__ Wvt,
    const float* __restrict__ bq, const float* __restrict__ bk, const float* __restrict__ bv,
    u16* __restrict__ QpT, u16* __restrict__ KpT, u16* __restrict__ Vp)
{
    const int z = blockIdx.z;
    const u16* A    = z == 0 ? qb  : z == 1 ? kb  : vb;
    const u16* Bt   = z == 0 ? Wqt : z == 1 ? Wkt : Wvt;
    const float* bias = z == 0 ? bq : z == 1 ? bk : bv;

    __shared__ __align__(16) u16 smem[16384];   // 32 KB exactly
    u16* As = smem;
    u16* Bs = smem + 8192;

    const int t    = threadIdx.x;
    const int lane = t & 63;
    const int wave = t >> 6;
    const int wr   = wave >> 1;
    const int wc   = wave & 1;
    const int quad = lane >> 4;
    const int l16  = lane & 15;
    const int m0   = blockIdx.x * 128;
    const int n0   = blockIdx.y * 128;
    const int K    = DM_;

    f32x4 acc[4][4] = {};

    for (int kt = 0; kt < K; kt += 64) {
#pragma unroll
        for (int i = 0; i < 4; ++i) {
            int c   = i * 256 + t;
            int row = c >> 3;
            int kc  = c & 7;
            int cbase = i * 256 + wave * 64;
            const u16* gA = A  + (size_t)(m0 + row) * K + kt + kc * 8;
            const u16* gB = Bt + (size_t)(n0 + row) * K + kt + kc * 8;
            __builtin_amdgcn_global_load_lds((as1_cvp)gA, (as3_vp)(As + cbase * 8), 16, 0, 0);
            __builtin_amdgcn_global_load_lds((as1_cvp)gB, (as3_vp)(Bs + cbase * 8), 16, 0, 0);
        }
        __syncthreads();
#pragma unroll
        for (int ks = 0; ks < 2; ++ks) {
            bf16x8 af[4], bfr[4];
#pragma unroll
            for (int it = 0; it < 4; ++it)
                af[it] = *(const bf16x8*)(As + (wr * 64 + it * 16 + l16) * 64 + ks * 32 + quad * 8);
#pragma unroll
            for (int jt = 0; jt < 4; ++jt)
                bfr[jt] = *(const bf16x8*)(Bs + (wc * 64 + jt * 16 + l16) * 64 + ks * 32 + quad * 8);
#pragma unroll
            for (int it = 0; it < 4; ++it)
#pragma unroll
                for (int jt = 0; jt < 4; ++jt)
                    acc[it][jt] = __builtin_amdgcn_mfma_f32_16x16x32_bf16(
                        af[it], bfr[jt], acc[it][jt], 0, 0, 0);
        }
        __syncthreads();
    }

    if (z == 2) {
        // natural bf16 out (V)
#pragma unroll
        for (int it = 0; it < 4; ++it) {
            int row0 = m0 + wr * 64 + it * 16 + quad * 4;
#pragma unroll
            for (int jt = 0; jt < 4; ++jt) {
                int col = n0 + wc * 64 + jt * 16 + l16;
                float bv2 = bias[col];
#pragma unroll
                for (int r = 0; r < 4; ++r)
                    Vp[(size_t)(row0 + r) * DM_ + col] = f2b(acc[it][jt][r] + bv2);
            }
        }
    } else {
        // transposed per-head out (+ELU+1) via LDS: Ct[col][row], stride 128
        // (reuses As+Bs; one-time epilogue bank conflicts, worth +1 block/CU)
        u16* OutT = z == 0 ? QpT : KpT;
        u16* Ct = smem;
        __syncthreads();   // K-loop fragment reads fully done before overwrite
#pragma unroll
        for (int it = 0; it < 4; ++it) {
            int row0 = wr * 64 + it * 16 + quad * 4;
#pragma unroll
            for (int jt = 0; jt < 4; ++jt) {
                int colr = wc * 64 + jt * 16 + l16;
                float bv2 = bias[n0 + colr];
                float x0 = acc[it][jt][0] + bv2;
                float x1 = acc[it][jt][1] + bv2;
                float x2 = acc[it][jt][2] + bv2;
                float x3 = acc[it][jt][3] + bv2;
                x0 = (x0 > 0.f) ? (x0 + 1.f) : __expf(x0);
                x1 = (x1 > 0.f) ? (x1 + 1.f) : __expf(x1);
                x2 = (x2 > 0.f) ? (x2 + 1.f) : __expf(x2);
                x3 = (x3 > 0.f) ? (x3 + 1.f) : __expf(x3);
                ushort4 o;
                o.x = f2b(x0); o.y = f2b(x1); o.z = f2b(x2); o.w = f2b(x3);
                *(ushort4*)&Ct[colr * 128 + row0] = o;
            }
        }
        __syncthreads();
        int b   = m0 >> 12;
        int seg = t & 15;
        int cg  = t >> 4;
#pragma unroll
        for (int iter = 0; iter < 8; ++iter) {
            int colIdx = iter * 16 + cg;
            int gcol = n0 + colIdx;
            int bh = b * 16 + (gcol >> 6);
            int e  = gcol & 63;
            uint4 v = *(const uint4*)&Ct[colIdx * 128 + seg * 8];
            *(uint4*)(OutT + ((size_t)bh << 18) + ((size_t)e << 12)
                      + (m0 & 4095) + seg * 8) = v;
        }
    }
}

// ---------------------------------------------------------------------------
// Final projection: C = ctx @ Wot^T + bo, fp32 out.
// 64x128 tile -> 1024 blocks (5 blocks/CU by LDS 24 KB) to escape the
// 2-blocks/CU low-residency regime of the 128x128 tiling at this shape.
// ---------------------------------------------------------------------------
__global__ __launch_bounds__(256, 5) void gemm_out_kernel(
    const u16* __restrict__ A, const u16* __restrict__ Bt,
    const float* __restrict__ bias, float* __restrict__ Cout)
{
    __shared__ __align__(16) u16 smem[12288];   // As 64x64 + Bs 128x64
    u16* As = smem;          // 4096 u16
    u16* Bs = smem + 4096;   // 8192 u16

    const int t    = threadIdx.x;
    const int lane = t & 63;
    const int wave = t >> 6;
    const int wr   = wave >> 1;     // m half (0..1), 32 rows each
    const int wc   = wave & 1;      // n half (0..1), 64 cols each
    const int quad = lane >> 4;
    const int l16  = lane & 15;
    const int m0   = blockIdx.x * 64;
    const int n0   = blockIdx.y * 128;
    const int K    = DM_;

    f32x4 acc[2][4] = {};

    for (int kt = 0; kt < K; kt += 64) {
        // A: 512 chunks (64 rows x 8), B: 1024 chunks (128 rows x 8)
#pragma unroll
        for (int i = 0; i < 2; ++i) {
            int c   = i * 256 + t;
            int row = c >> 3;
            int kc  = c & 7;
            int cbase = i * 256 + wave * 64;
            const u16* gA = A + (size_t)(m0 + row) * K + kt + kc * 8;
            __builtin_amdgcn_global_load_lds((as1_cvp)gA, (as3_vp)(As + cbase * 8), 16, 0, 0);
        }
#pragma unroll
        for (int i = 0; i < 4; ++i) {
            int c   = i * 256 + t;
            int row = c >> 3;
            int kc  = c & 7;
            int cbase = i * 256 + wave * 64;
            const u16* gB = Bt + (size_t)(n0 + row) * K + kt + kc * 8;
            __builtin_amdgcn_global_load_lds((as1_cvp)gB, (as3_vp)(Bs + cbase * 8), 16, 0, 0);
        }
        __syncthreads();
#pragma unroll
        for (int ks = 0; ks < 2; ++ks) {
            bf16x8 af[2], bfr[4];
#pragma unroll
            for (int it = 0; it < 2; ++it)
                af[it] = *(const bf16x8*)(As + (wr * 32 + it * 16 + l16) * 64 + ks * 32 + quad * 8);
#pragma unroll
            for (int jt = 0; jt < 4; ++jt)
                bfr[jt] = *(const bf16x8*)(Bs + (wc * 64 + jt * 16 + l16) * 64 + ks * 32 + quad * 8);
#pragma unroll
            for (int it = 0; it < 2; ++it)
#pragma unroll
                for (int jt = 0; jt < 4; ++jt)
                    acc[it][jt] = __builtin_amdgcn_mfma_f32_16x16x32_bf16(
                        af[it], bfr[jt], acc[it][jt], 0, 0, 0);
        }
        __syncthreads();
    }

#pragma unroll
    for (int it = 0; it < 2; ++it) {
        int row0 = m0 + wr * 32 + it * 16 + quad * 4;
#pragma unroll
        for (int jt = 0; jt < 4; ++jt) {
            int col = n0 + wc * 64 + jt * 16 + l16;
            float bv = bias[col];
#pragma unroll
            for (int r = 0; r < 4; ++r)
                Cout[(size_t)(row0 + r) * DM_ + col] = acc[it][jt][r] + bv;
        }
    }
}

// ---------------------------------------------------------------------------
// attn_s: S_part[y][bh][e][d] = sum_{l in chunk y} KpT[bh][e][l]*QpT[bh][d][l]
// (non-atomic partials; attn_out sums the 8 parts during staging)
// + denom[bh][l] = sum_e QpT[e][l]*KpT[e][l] + 1e-6
// ---------------------------------------------------------------------------
__global__ __launch_bounds__(256) void attn_s_kernel(
    const u16* __restrict__ QpT, const u16* __restrict__ KpT,
    float* __restrict__ S_part, float* __restrict__ denom)
{
    const int t    = threadIdx.x;
    const int lane = t & 63;
    const int wave = t >> 6;
    const int quad = lane >> 4;
    const int l16  = lane & 15;
    const int bh   = blockIdx.x;
    const int lc   = blockIdx.y * 512;

    const u16* baseQ = QpT + ((size_t)bh << 18);
    const u16* baseK = KpT + ((size_t)bh << 18);

    f32x4 acc[4] = {};
    const u16* arow = baseK + (size_t)(wave * 16 + l16) * 4096 + lc;
#pragma unroll 4
    for (int ks = 0; ks < 16; ++ks) {
        int koff = ks * 32 + quad * 8;
        bf16x8 a = *(const bf16x8*)(arow + koff);
#pragma unroll
        for (int dt = 0; dt < 4; ++dt) {
            bf16x8 b = *(const bf16x8*)(baseQ + (size_t)(dt * 16 + l16) * 4096 + lc + koff);
            acc[dt] = __builtin_amdgcn_mfma_f32_16x16x32_bf16(a, b, acc[dt], 0, 0, 0);
        }
    }
    float* Sp = S_part + ((size_t)blockIdx.y * 32 + bh) * 4096;
#pragma unroll
    for (int dt = 0; dt < 4; ++dt)
#pragma unroll
        for (int r = 0; r < 4; ++r)
            Sp[(wave * 16 + quad * 4 + r) * 64 + dt * 16 + l16] = acc[dt][r];

    // denom: all 256 threads, 2 consecutive l each -> covers 512 l
    {
        float s0 = 0.f, s1 = 0.f;
        int off = lc + 2 * t;
#pragma unroll 8
        for (int e = 0; e < 64; ++e) {
            unsigned int qv = *(const unsigned int*)(baseQ + (size_t)e * 4096 + off);
            unsigned int kv = *(const unsigned int*)(baseK + (size_t)e * 4096 + off);
            s0 += b2f((u16)(qv & 0xffff)) * b2f((u16)(kv & 0xffff));
            s1 += b2f((u16)(qv >> 16))   * b2f((u16)(kv >> 16));
        }
        denom[(size_t)bh * 4096 + off]     = s0 + 1e-6f;
        denom[(size_t)bh * 4096 + off + 1] = s1 + 1e-6f;
    }
}

// ---------------------------------------------------------------------------
// attn_out: ctx[b][l][h*64+d] = (sum_e V[l][e] * S[e][d]) / denom[l]  (MFMA)
// S = sum of 8 partials (L2-resident, summed during staging).
// ---------------------------------------------------------------------------
__global__ __launch_bounds__(256) void attn_out_kernel(
    const u16* __restrict__ Vp, const float* __restrict__ S_part,
    const float* __restrict__ denom, u16* __restrict__ ctx)
{
    __shared__ __align__(16) u16 Sb[64 * 64];   // Sb[d][e], e contiguous
    __shared__ float dsh[256];
    const int t    = threadIdx.x;
    const int lane = t & 63;
    const int wave = t >> 6;
    const int quad = lane >> 4;
    const int l16  = lane & 15;
    const int bh   = blockIdx.x;
    const int b    = bh >> 4, h = bh & 15;
    const int lc   = blockIdx.y * 256;

    {
        const float* Sg = S_part + (size_t)bh * 4096;
        int e = t >> 2, d0 = (t & 3) * 16;
        float tmp[16];
#pragma unroll
        for (int i = 0; i < 16; ++i) tmp[i] = 0.f;
#pragma unroll
        for (int p = 0; p < 8; ++p) {
            const float* Sgp = Sg + (size_t)p * 32 * 4096;
#pragma unroll
            for (int i = 0; i < 16; ++i) tmp[i] += Sgp[e * 64 + d0 + i];
        }
#pragma unroll
        for (int i = 0; i < 16; ++i)
            Sb[(d0 + i) * 64 + e] = f2b(tmp[i]);
        dsh[t] = denom[(size_t)bh * 4096 + lc + t];
    }
    __syncthreads();

    const u16* Abase = Vp + (size_t)b * L_ * DM_ + (size_t)(lc + wave * 64 + l16) * DM_ + h * 64;
    f32x4 acc[4][4] = {};
#pragma unroll
    for (int ks = 0; ks < 2; ++ks) {
        int koff = ks * 32 + quad * 8;
        bf16x8 af[4], bfr[4];
#pragma unroll
        for (int lt = 0; lt < 4; ++lt)
            af[lt] = *(const bf16x8*)(Abase + (size_t)(lt * 16) * DM_ + koff);
#pragma unroll
        for (int dt = 0; dt < 4; ++dt)
            bfr[dt] = *(const bf16x8*)(Sb + (dt * 16 + l16) * 64 + koff);
#pragma unroll
        for (int lt = 0; lt < 4; ++lt)
#pragma unroll
            for (int dt = 0; dt < 4; ++dt)
                acc[lt][dt] = __builtin_amdgcn_mfma_f32_16x16x32_bf16(
                    af[lt], bfr[dt], acc[lt][dt], 0, 0, 0);
    }

    u16* cbase = ctx + (size_t)b * L_ * DM_ + h * 64;
#pragma unroll
    for (int lt = 0; lt < 4; ++lt) {
        int lrow0 = wave * 64 + lt * 16 + quad * 4;
        float inv[4];
#pragma unroll
        for (int r = 0; r < 4; ++r) inv[r] = 1.f / dsh[lrow0 + r];
#pragma unroll
        for (int dt = 0; dt < 4; ++dt) {
            int d = dt * 16 + l16;
#pragma unroll
            for (int r = 0; r < 4; ++r)
                cbase[(size_t)(lc + lrow0 + r) * DM_ + d] = f2b(acc[lt][dt][r] * inv[r]);
        }
    }
}

// ---------------------------------------------------------------------------
extern "C" void kernel_launch(void* const* d_in, const int* in_sizes, int n_in,
                              void* d_out, int out_size, void* d_ws, size_t ws_size,
                              hipStream_t stream)
{
    const float* query = (const float*)d_in[0];
    const float* key   = (const float*)d_in[1];
    const float* value = (const float*)d_in[2];
    const float* Wq = (const float*)d_in[3];  const float* bq = (const float*)d_in[4];
    const float* Wk = (const float*)d_in[5];  const float* bk = (const float*)d_in[6];
    const float* Wv = (const float*)d_in[7];  const float* bv = (const float*)d_in[8];
    const float* Wo = (const float*)d_in[9];  const float* bo = (const float*)d_in[10];

    const size_t SZ = (size_t)M_ * DM_ * sizeof(u16);   // 16.78 MB per bf16 tensor
    char* ws = (char*)d_ws;
    u16* qb  = (u16*)(ws + 0 * SZ);
    u16* kb  = (u16*)(ws + 1 * SZ);
    u16* vb  = (u16*)(ws + 2 * SZ);
    u16* QpT = (u16*)(ws + 3 * SZ);   // [bh][e][l] l-contiguous
    u16* KpT = (u16*)(ws + 4 * SZ);
    u16* Vp  = (u16*)(ws + 5 * SZ);
    u16* ctx = (u16*)(ws + 6 * SZ);
    u16* Wqt = (u16*)(ws + 7 * SZ);
    u16* Wkt = Wqt + (size_t)DM_ * DM_;
    u16* Wvt = Wkt + (size_t)DM_ * DM_;
    u16* Wot = Wvt + (size_t)DM_ * DM_;
    float* S_part = (float*)(ws + 7 * SZ + 4 * (size_t)DM_ * DM_ * sizeof(u16));
    float* denom  = S_part + (size_t)8 * 32 * 4096;     // 8 parts x 32 bh x 4096

    // 1. prep: q/k/v cast + 4 weight transposes, one launch
    prep_kernel<<<28672, 256, 0, stream>>>(
        query, key, value, qb, kb, vb, Wq, Wk, Wv, Wo, Wqt, Wkt, Wvt, Wot);

    // 2. QKV projections, one launch
    gemm_qkv_kernel<<<dim3(M_ / 128, DM_ / 128, 3), 256, 0, stream>>>(
        qb, kb, vb, Wqt, Wkt, Wvt, bq, bk, bv, QpT, KpT, Vp);

    // 3. S partials = K^T Q per head (+denom), MFMA over l, 512 l/block
    attn_s_kernel<<<dim3(B_ * H_, L_ / 512), 256, 0, stream>>>(QpT, KpT, S_part, denom);

    // 4. out = V S / denom -> ctx (bf16, combined-head layout), MFMA
    attn_out_kernel<<<dim3(B_ * H_, L_ / 256), 256, 0, stream>>>(Vp, S_part, denom, ctx);

    // 5. final projection -> fp32 d_out (64x128 tile, 1024 blocks)
    gemm_out_kernel<<<dim3(M_ / 64, DM_ / 128), 256, 0, stream>>>(
        ctx, Wot, bo, (float*)d_out);
}

// Round 6
// 284.236 us; speedup vs baseline: 1.0123x; 1.0123x over previous
//
#include <hip/hip_runtime.h>

#define B_  2
#define L_  4096
#define DM_ 1024
#define H_  16
#define D_  64
#define M_  (B_ * L_)   // 8192

typedef unsigned short u16;
typedef short bf16x8 __attribute__((ext_vector_type(8)));   // 8 bf16 (4 VGPRs)
typedef float f32x4  __attribute__((ext_vector_type(4)));   // MFMA accumulator

typedef const __attribute__((address_space(1))) void* as1_cvp;
typedef __attribute__((address_space(3))) void* as3_vp;

__device__ __forceinline__ float b2f(u16 u) {
    union { unsigned int i; float f; } x; x.i = ((unsigned int)u) << 16; return x.f;
}
__device__ __forceinline__ u16 f2b(float f) {   // RNE bf16
    unsigned int x = __float_as_uint(f);
    return (u16)((x + 0x7fffu + ((x >> 16) & 1u)) >> 16);
}

// ---------------------------------------------------------------------------
// prep: blocks [0,12288): fp32->bf16 cast of q/k/v, 8 elems/thread
//       blocks [12288,16384): W transpose+cast, 1024 blocks per weight
// ---------------------------------------------------------------------------
__global__ void prep_kernel(
    const float* __restrict__ query, const float* __restrict__ key, const float* __restrict__ value,
    u16* __restrict__ qb, u16* __restrict__ kb, u16* __restrict__ vb,
    const float* __restrict__ w0, const float* __restrict__ w1,
    const float* __restrict__ w2, const float* __restrict__ w3,
    u16* __restrict__ t0, u16* __restrict__ t1, u16* __restrict__ t2, u16* __restrict__ t3)
{
    __shared__ float tile[32][33];
    const int bx = blockIdx.x;
    const int t  = threadIdx.x;
    if (bx < 12288) {
        int z = bx >> 12;                 // /4096
        int i = (bx & 4095) * 256 + t;    // 8-elem group index
        const float* in = z == 0 ? query : (z == 1 ? key : value);
        u16* out        = z == 0 ? qb    : (z == 1 ? kb  : vb);
        float4 v0 = ((const float4*)in)[2 * i];
        float4 v1 = ((const float4*)in)[2 * i + 1];
        ushort4 o0, o1;
        o0.x = f2b(v0.x); o0.y = f2b(v0.y); o0.z = f2b(v0.z); o0.w = f2b(v0.w);
        o1.x = f2b(v1.x); o1.y = f2b(v1.y); o1.z = f2b(v1.z); o1.w = f2b(v1.w);
        ((ushort4*)out)[2 * i]     = o0;
        ((ushort4*)out)[2 * i + 1] = o1;
    } else {
        int bz = bx - 12288;
        int z  = bz >> 10;
        int rem = bz & 1023;
        int gx = rem & 31, gy = rem >> 5;
        const float* W = z == 0 ? w0 : z == 1 ? w1 : z == 2 ? w2 : w3;
        u16* Wt        = z == 0 ? t0 : z == 1 ? t1 : z == 2 ? t2 : t3;
        int tx = t & 31, ty = t >> 5;     // 32 x 8
        int n  = gx * 32 + tx;
        int k0 = gy * 32;
#pragma unroll
        for (int i = 0; i < 4; ++i)
            tile[ty + i * 8][tx] = W[(size_t)(k0 + ty + i * 8) * DM_ + n];
        __syncthreads();
#pragma unroll
        for (int i = 0; i < 4; ++i) {
            int nn = gx * 32 + ty + i * 8;
            Wt[(size_t)nn * DM_ + k0 + tx] = f2b(tile[tx][ty + i * 8]);
        }
    }
}

// ---------------------------------------------------------------------------
// QKV projections batched via blockIdx.z (z=0:Q, 1:K -> per-head transposed
// +ELU+1 out; z=2:V -> natural bf16 out).
// XOR-swizzled LDS: chunk slot (row,s) holds global kc = s ^ (row&7); the
// fragment read for row r, chunk kc is at slot kc ^ (l16&7) -> 32-bank spread
// (2-way only, free per m136) instead of 16-way same-bank.
// ---------------------------------------------------------------------------
__global__ __launch_bounds__(256, 4) void gemm_qkv_kernel(
    const u16* __restrict__ qb, const u16* __restrict__ kb, const u16* __restrict__ vb,
    const u16* __restrict__ Wqt, const u16* __restrict__ Wkt, const u16* __restrict__ Wvt,
    const float* __restrict__ bq, const float* __restrict__ bk, const float* __restrict__ bv,
    u16* __restrict__ QpT, u16* __restrict__ KpT, u16* __restrict__ Vp)
{
    const int z = blockIdx.z;
    const u16* A    = z == 0 ? qb  : z == 1 ? kb  : vb;
    const u16* Bt   = z == 0 ? Wqt : z == 1 ? Wkt : Wvt;
    const float* bias = z == 0 ? bq : z == 1 ? bk : bv;

    __shared__ __align__(16) u16 smem[17408];   // As+Bs 32 KB; Ct 128x136
    u16* As = smem;
    u16* Bs = smem + 8192;

    const int t    = threadIdx.x;
    const int lane = t & 63;
    const int wave = t >> 6;
    const int wr   = wave >> 1;
    const int wc   = wave & 1;
    const int quad = lane >> 4;
    const int l16  = lane & 15;
    const int swz  = l16 & 7;       // fragment-read chunk swizzle
    const int m0   = blockIdx.x * 128;
    const int n0   = blockIdx.y * 128;
    const int K    = DM_;

    f32x4 acc[4][4] = {};

    for (int kt = 0; kt < K; kt += 64) {
#pragma unroll
        for (int i = 0; i < 4; ++i) {
            int c   = i * 256 + t;
            int row = c >> 3;
            int kc  = (c & 7) ^ (row & 7);     // source chunk for this slot
            int cbase = i * 256 + wave * 64;
            const u16* gA = A  + (size_t)(m0 + row) * K + kt + kc * 8;
            const u16* gB = Bt + (size_t)(n0 + row) * K + kt + kc * 8;
            __builtin_amdgcn_global_load_lds((as1_cvp)gA, (as3_vp)(As + cbase * 8), 16, 0, 0);
            __builtin_amdgcn_global_load_lds((as1_cvp)gB, (as3_vp)(Bs + cbase * 8), 16, 0, 0);
        }
        __syncthreads();
#pragma unroll
        for (int ks = 0; ks < 2; ++ks) {
            int skc = (ks * 4 + quad) ^ swz;   // swizzled chunk slot
            bf16x8 af[4], bfr[4];
#pragma unroll
            for (int it = 0; it < 4; ++it)
                af[it] = *(const bf16x8*)(As + (wr * 64 + it * 16 + l16) * 64 + skc * 8);
#pragma unroll
            for (int jt = 0; jt < 4; ++jt)
                bfr[jt] = *(const bf16x8*)(Bs + (wc * 64 + jt * 16 + l16) * 64 + skc * 8);
#pragma unroll
            for (int it = 0; it < 4; ++it)
#pragma unroll
                for (int jt = 0; jt < 4; ++jt)
                    acc[it][jt] = __builtin_amdgcn_mfma_f32_16x16x32_bf16(
                        af[it], bfr[jt], acc[it][jt], 0, 0, 0);
        }
        __syncthreads();
    }

    if (z == 2) {
        // natural bf16 out (V)
#pragma unroll
        for (int it = 0; it < 4; ++it) {
            int row0 = m0 + wr * 64 + it * 16 + quad * 4;
#pragma unroll
            for (int jt = 0; jt < 4; ++jt) {
                int col = n0 + wc * 64 + jt * 16 + l16;
                float bv2 = bias[col];
#pragma unroll
                for (int r = 0; r < 4; ++r)
                    Vp[(size_t)(row0 + r) * DM_ + col] = f2b(acc[it][jt][r] + bv2);
            }
        }
    } else {
        // transposed per-head out (+ELU+1) via LDS: Ct[col][row], stride 136
        u16* OutT = z == 0 ? QpT : KpT;
        u16* Ct = smem;   // safe: K-loop ends with __syncthreads
#pragma unroll
        for (int it = 0; it < 4; ++it) {
            int row0 = wr * 64 + it * 16 + quad * 4;
#pragma unroll
            for (int jt = 0; jt < 4; ++jt) {
                int colr = wc * 64 + jt * 16 + l16;
                float bv2 = bias[n0 + colr];
                float x0 = acc[it][jt][0] + bv2;
                float x1 = acc[it][jt][1] + bv2;
                float x2 = acc[it][jt][2] + bv2;
                float x3 = acc[it][jt][3] + bv2;
                x0 = (x0 > 0.f) ? (x0 + 1.f) : __expf(x0);
                x1 = (x1 > 0.f) ? (x1 + 1.f) : __expf(x1);
                x2 = (x2 > 0.f) ? (x2 + 1.f) : __expf(x2);
                x3 = (x3 > 0.f) ? (x3 + 1.f) : __expf(x3);
                ushort4 o;
                o.x = f2b(x0); o.y = f2b(x1); o.z = f2b(x2); o.w = f2b(x3);
                *(ushort4*)&Ct[colr * 136 + row0] = o;
            }
        }
        __syncthreads();
        int b   = m0 >> 12;
        int seg = t & 15;
        int cg  = t >> 4;
#pragma unroll
        for (int iter = 0; iter < 8; ++iter) {
            int colIdx = iter * 16 + cg;
            int gcol = n0 + colIdx;
            int bh = b * 16 + (gcol >> 6);
            int e  = gcol & 63;
            uint4 v = *(const uint4*)&Ct[colIdx * 136 + seg * 8];
            *(uint4*)(OutT + ((size_t)bh << 18) + ((size_t)e << 12)
                      + (m0 & 4095) + seg * 8) = v;
        }
    }
}

// ---------------------------------------------------------------------------
// Final projection: C = ctx @ Wot^T + bo, fp32 out. 64x128 tile, swizzled LDS.
// ---------------------------------------------------------------------------
__global__ __launch_bounds__(256, 5) void gemm_out_kernel(
    const u16* __restrict__ A, const u16* __restrict__ Bt,
    const float* __restrict__ bias, float* __restrict__ Cout)
{
    __shared__ __align__(16) u16 smem[12288];   // As 64x64 + Bs 128x64
    u16* As = smem;          // 4096 u16
    u16* Bs = smem + 4096;   // 8192 u16

    const int t    = threadIdx.x;
    const int lane = t & 63;
    const int wave = t >> 6;
    const int wr   = wave >> 1;
    const int wc   = wave & 1;
    const int quad = lane >> 4;
    const int l16  = lane & 15;
    const int swz  = l16 & 7;
    const int m0   = blockIdx.x * 64;
    const int n0   = blockIdx.y * 128;
    const int K    = DM_;

    f32x4 acc[2][4] = {};

    for (int kt = 0; kt < K; kt += 64) {
#pragma unroll
        for (int i = 0; i < 2; ++i) {
            int c   = i * 256 + t;
            int row = c >> 3;
            int kc  = (c & 7) ^ (row & 7);
            int cbase = i * 256 + wave * 64;
            const u16* gA = A + (size_t)(m0 + row) * K + kt + kc * 8;
            __builtin_amdgcn_global_load_lds((as1_cvp)gA, (as3_vp)(As + cbase * 8), 16, 0, 0);
        }
#pragma unroll
        for (int i = 0; i < 4; ++i) {
            int c   = i * 256 + t;
            int row = c >> 3;
            int kc  = (c & 7) ^ (row & 7);
            int cbase = i * 256 + wave * 64;
            const u16* gB = Bt + (size_t)(n0 + row) * K + kt + kc * 8;
            __builtin_amdgcn_global_load_lds((as1_cvp)gB, (as3_vp)(Bs + cbase * 8), 16, 0, 0);
        }
        __syncthreads();
#pragma unroll
        for (int ks = 0; ks < 2; ++ks) {
            int skc = (ks * 4 + quad) ^ swz;
            bf16x8 af[2], bfr[4];
#pragma unroll
            for (int it = 0; it < 2; ++it)
                af[it] = *(const bf16x8*)(As + (wr * 32 + it * 16 + l16) * 64 + skc * 8);
#pragma unroll
            for (int jt = 0; jt < 4; ++jt)
                bfr[jt] = *(const bf16x8*)(Bs + (wc * 64 + jt * 16 + l16) * 64 + skc * 8);
#pragma unroll
            for (int it = 0; it < 2; ++it)
#pragma unroll
                for (int jt = 0; jt < 4; ++jt)
                    acc[it][jt] = __builtin_amdgcn_mfma_f32_16x16x32_bf16(
                        af[it], bfr[jt], acc[it][jt], 0, 0, 0);
        }
        __syncthreads();
    }

#pragma unroll
    for (int it = 0; it < 2; ++it) {
        int row0 = m0 + wr * 32 + it * 16 + quad * 4;
#pragma unroll
        for (int jt = 0; jt < 4; ++jt) {
            int col = n0 + wc * 64 + jt * 16 + l16;
            float bv = bias[col];
#pragma unroll
            for (int r = 0; r < 4; ++r)
                Cout[(size_t)(row0 + r) * DM_ + col] = acc[it][jt][r] + bv;
        }
    }
}

// ---------------------------------------------------------------------------
// attn_s: S_part[y][bh][e][d] = sum_{l in 1024-chunk y} KpT[e][l]*QpT[d][l]
// + denom[bh][l] = sum_e QpT[e][l]*KpT[e][l] + 1e-6  (4 l per thread)
// ---------------------------------------------------------------------------
__global__ __launch_bounds__(256) void attn_s_kernel(
    const u16* __restrict__ QpT, const u16* __restrict__ KpT,
    float* __restrict__ S_part, float* __restrict__ denom)
{
    const int t    = threadIdx.x;
    const int lane = t & 63;
    const int wave = t >> 6;
    const int quad = lane >> 4;
    const int l16  = lane & 15;
    const int bh   = blockIdx.x;
    const int lc   = blockIdx.y * 1024;

    const u16* baseQ = QpT + ((size_t)bh << 18);
    const u16* baseK = KpT + ((size_t)bh << 18);

    f32x4 acc[4] = {};
    const u16* arow = baseK + (size_t)(wave * 16 + l16) * 4096 + lc;
#pragma unroll 4
    for (int ks = 0; ks < 32; ++ks) {
        int koff = ks * 32 + quad * 8;
        bf16x8 a = *(const bf16x8*)(arow + koff);
#pragma unroll
        for (int dt = 0; dt < 4; ++dt) {
            bf16x8 b = *(const bf16x8*)(baseQ + (size_t)(dt * 16 + l16) * 4096 + lc + koff);
            acc[dt] = __builtin_amdgcn_mfma_f32_16x16x32_bf16(a, b, acc[dt], 0, 0, 0);
        }
    }
    float* Sp = S_part + ((size_t)blockIdx.y * 32 + bh) * 4096;
#pragma unroll
    for (int dt = 0; dt < 4; ++dt)
#pragma unroll
        for (int r = 0; r < 4; ++r)
            Sp[(wave * 16 + quad * 4 + r) * 64 + dt * 16 + l16] = acc[dt][r];

    // denom: 4 consecutive l per thread (covers 1024)
    {
        float s0 = 0.f, s1 = 0.f, s2 = 0.f, s3 = 0.f;
        int off = lc + 4 * t;
#pragma unroll 8
        for (int e = 0; e < 64; ++e) {
            uint2 qv = *(const uint2*)(baseQ + (size_t)e * 4096 + off);
            uint2 kv = *(const uint2*)(baseK + (size_t)e * 4096 + off);
            s0 += b2f((u16)(qv.x & 0xffff)) * b2f((u16)(kv.x & 0xffff));
            s1 += b2f((u16)(qv.x >> 16))   * b2f((u16)(kv.x >> 16));
            s2 += b2f((u16)(qv.y & 0xffff)) * b2f((u16)(kv.y & 0xffff));
            s3 += b2f((u16)(qv.y >> 16))   * b2f((u16)(kv.y >> 16));
        }
        float* dp = denom + (size_t)bh * 4096 + off;
        dp[0] = s0 + 1e-6f; dp[1] = s1 + 1e-6f;
        dp[2] = s2 + 1e-6f; dp[3] = s3 + 1e-6f;
    }
}

// ---------------------------------------------------------------------------
// attn_out: ctx[b][l][h*64+d] = (sum_e V[l][e] * S[e][d]) / denom[l]  (MFMA)
// S = sum of 4 partials. Sb is XOR-swizzled: (d, e-chunk c) at slot c^(d&7).
// ---------------------------------------------------------------------------
__global__ __launch_bounds__(256) void attn_out_kernel(
    const u16* __restrict__ Vp, const float* __restrict__ S_part,
    const float* __restrict__ denom, u16* __restrict__ ctx)
{
    __shared__ __align__(16) u16 Sb[64 * 64];   // Sb[d][e] swizzled
    __shared__ float dsh[256];
    const int t    = threadIdx.x;
    const int lane = t & 63;
    const int wave = t >> 6;
    const int quad = lane >> 4;
    const int l16  = lane & 15;
    const int bh   = blockIdx.x;
    const int b    = bh >> 4, h = bh & 15;
    const int lc   = blockIdx.y * 256;

    {
        const float* Sg = S_part + (size_t)bh * 4096;
        int e = t >> 2, d0 = (t & 3) * 16;
        float tmp[16];
#pragma unroll
        for (int i = 0; i < 16; ++i) tmp[i] = 0.f;
#pragma unroll
        for (int p = 0; p < 4; ++p) {
            const float* Sgp = Sg + (size_t)p * 32 * 4096;
#pragma unroll
            for (int i = 0; i < 16; ++i) tmp[i] += Sgp[e * 64 + d0 + i];
        }
        int ec = e >> 3, el = e & 7;   // e chunk / within-chunk
#pragma unroll
        for (int i = 0; i < 16; ++i) {
            int d = d0 + i;
            Sb[d * 64 + ((ec ^ (d & 7)) << 3) + el] = f2b(tmp[i]);
        }
        dsh[t] = denom[(size_t)bh * 4096 + lc + t];
    }
    __syncthreads();

    const u16* Abase = Vp + (size_t)b * L_ * DM_ + (size_t)(lc + wave * 64 + l16) * DM_ + h * 64;
    f32x4 acc[4][4] = {};
#pragma unroll
    for (int ks = 0; ks < 2; ++ks) {
        int koff = ks * 32 + quad * 8;
        int kc   = ks * 4 + quad;
        bf16x8 af[4], bfr[4];
#pragma unroll
        for (int lt = 0; lt < 4; ++lt)
            af[lt] = *(const bf16x8*)(Abase + (size_t)(lt * 16) * DM_ + koff);
#pragma unroll
        for (int dt = 0; dt < 4; ++dt) {
            int d = dt * 16 + l16;
            bfr[dt] = *(const bf16x8*)(Sb + d * 64 + ((kc ^ (d & 7)) << 3));
        }
#pragma unroll
        for (int lt = 0; lt < 4; ++lt)
#pragma unroll
            for (int dt = 0; dt < 4; ++dt)
                acc[lt][dt] = __builtin_amdgcn_mfma_f32_16x16x32_bf16(
                    af[lt], bfr[dt], acc[lt][dt], 0, 0, 0);
    }

    u16* cbase = ctx + (size_t)b * L_ * DM_ + h * 64;
#pragma unroll
    for (int lt = 0; lt < 4; ++lt) {
        int lrow0 = wave * 64 + lt * 16 + quad * 4;
        float inv[4];
#pragma unroll
        for (int r = 0; r < 4; ++r) inv[r] = 1.f / dsh[lrow0 + r];
#pragma unroll
        for (int dt = 0; dt < 4; ++dt) {
            int d = dt * 16 + l16;
#pragma unroll
            for (int r = 0; r < 4; ++r)
                cbase[(size_t)(lc + lrow0 + r) * DM_ + d] = f2b(acc[lt][dt][r] * inv[r]);
        }
    }
}

// ---------------------------------------------------------------------------
extern "C" void kernel_launch(void* const* d_in, const int* in_sizes, int n_in,
                              void* d_out, int out_size, void* d_ws, size_t ws_size,
                              hipStream_t stream)
{
    const float* query = (const float*)d_in[0];
    const float* key   = (const float*)d_in[1];
    const float* value = (const float*)d_in[2];
    const float* Wq = (const float*)d_in[3];  const float* bq = (const float*)d_in[4];
    const float* Wk = (const float*)d_in[5];  const float* bk = (const float*)d_in[6];
    const float* Wv = (const float*)d_in[7];  const float* bv = (const float*)d_in[8];
    const float* Wo = (const float*)d_in[9];  const float* bo = (const float*)d_in[10];

    const size_t SZ = (size_t)M_ * DM_ * sizeof(u16);   // 16.78 MB per bf16 tensor
    char* ws = (char*)d_ws;
    u16* qb  = (u16*)(ws + 0 * SZ);
    u16* kb  = (u16*)(ws + 1 * SZ);
    u16* vb  = (u16*)(ws + 2 * SZ);
    u16* QpT = (u16*)(ws + 3 * SZ);   // [bh][e][l] l-contiguous
    u16* KpT = (u16*)(ws + 4 * SZ);
    u16* Vp  = (u16*)(ws + 5 * SZ);
    u16* ctx = (u16*)(ws + 6 * SZ);
    u16* Wqt = (u16*)(ws + 7 * SZ);
    u16* Wkt = Wqt + (size_t)DM_ * DM_;
    u16* Wvt = Wkt + (size_t)DM_ * DM_;
    u16* Wot = Wvt + (size_t)DM_ * DM_;
    float* S_part = (float*)(ws + 7 * SZ + 4 * (size_t)DM_ * DM_ * sizeof(u16));
    float* denom  = S_part + (size_t)4 * 32 * 4096;     // 4 parts x 32 bh x 4096

    // 1. prep: q/k/v cast + 4 weight transposes, one launch
    prep_kernel<<<16384, 256, 0, stream>>>(
        query, key, value, qb, kb, vb, Wq, Wk, Wv, Wo, Wqt, Wkt, Wvt, Wot);

    // 2. QKV projections, one launch
    gemm_qkv_kernel<<<dim3(M_ / 128, DM_ / 128, 3), 256, 0, stream>>>(
        qb, kb, vb, Wqt, Wkt, Wvt, bq, bk, bv, QpT, KpT, Vp);

    // 3. S partials = K^T Q per head (+denom), MFMA over l, 1024 l/block
    attn_s_kernel<<<dim3(B_ * H_, L_ / 1024), 256, 0, stream>>>(QpT, KpT, S_part, denom);

    // 4. out = V S / denom -> ctx (bf16, combined-head layout), MFMA
    attn_out_kernel<<<dim3(B_ * H_, L_ / 256), 256, 0, stream>>>(Vp, S_part, denom, ctx);

    // 5. final projection -> fp32 d_out (64x128 tile, 1024 blocks)
    gemm_out_kernel<<<dim3(M_ / 64, DM_ / 128), 256, 0, stream>>>(
        ctx, Wot, bo, (float*)d_out);
}